// Round 12
// baseline (317.148 us; speedup 1.0000x reference)
//
#include <hip/hip_runtime.h>

static constexpr int NN = 100000;    // nodes
static constexpr int EE = 1600000;   // edges (before self-loops)
static constexpr int BSZ = 64;       // nodes per bucket
static constexpr int NB = (NN + BSZ - 1) / BSZ;   // 1563 buckets
static constexpr int BCAP = 2048;    // fixed bucket capacity (mean 1024, 32 sigma)
static constexpr int TILE = 4096;    // edges per binning block (391 blocks, r11-proven)
static constexpr int GB = 2048;      // gather blocks (persistent)

// ---- bf16 helpers (storage-only; math stays fp32) ----

__device__ __forceinline__ unsigned short f2bf(float f) {   // round-to-nearest-even
    unsigned u = __float_as_uint(f);
    u += 0x7FFFu + ((u >> 16) & 1u);
    return (unsigned short)(u >> 16);
}
__device__ __forceinline__ float bfl(unsigned u) { return __uint_as_float(u << 16); }
__device__ __forceinline__ float bfh(unsigned u) { return __uint_as_float(u & 0xFFFF0000u); }

typedef __attribute__((ext_vector_type(8))) short short8;    // 8 bf16 (4 VGPRs)
typedef __attribute__((ext_vector_type(4))) float float4v;   // MFMA acc

// ---------------- init: W^T bf16 prep + bucket cursor bases ----------------

__global__ __launch_bounds__(256) void k_init(const float* __restrict__ W1,
                                              const float* __restrict__ W2,
                                              unsigned short* __restrict__ W1t,
                                              unsigned short* __restrict__ W2t,
                                              int* __restrict__ bcur) {
    int idx = blockIdx.x * 256 + threadIdx.x;
    if (idx < 16384) {
        int n = idx >> 7, k = idx & 127;
        W1t[idx] = f2bf(W1[k * 128 + n]);
    } else if (idx < 24576) {
        int j = idx - 16384;
        int n = j >> 7, k = j & 127;
        W2t[j] = f2bf(W2[k * 64 + n]);
    } else if (idx < 24576 + NB) {
        int b = idx - 24576;
        bcur[b] = b * BCAP;
    }
}

// ---------------- bin edges into fixed-stride bucket chunks ----------------

__global__ __launch_bounds__(256) void k_bin(const int* __restrict__ src,
                                             const int* __restrict__ dst,
                                             int* __restrict__ bcur,
                                             int* __restrict__ ebuf, int E) {
    constexpr int K = TILE / 256;  // 16 edges per thread
    __shared__ int lcnt[NB];
    __shared__ int lbase[NB];
    const int t = threadIdx.x;
    const int e0 = blockIdx.x * TILE;

    for (int i = t; i < NB; i += 256) lcnt[i] = 0;
    __syncthreads();

    int dreg[K], ofs[K];
#pragma unroll
    for (int k = 0; k < K; ++k) {
        int e = e0 + k * 256 + t;
        if (e < E) {
            int d = dst[e];
            dreg[k] = d;
            ofs[k] = atomicAdd(&lcnt[d >> 6], 1);
        } else dreg[k] = -1;
    }
    __syncthreads();

    for (int i = t; i < NB; i += 256) {
        int c = lcnt[i];
        lbase[i] = c ? atomicAdd(&bcur[i], c) : 0;
    }
    __syncthreads();

#pragma unroll
    for (int k = 0; k < K; ++k) {
        if (dreg[k] >= 0) {
            int e = e0 + k * 256 + t;
            int s = src[e];
            int b = dreg[k] >> 6;
            ebuf[lbase[b] + ofs[k]] = (s << 6) | (dreg[k] & 63);
        }
    }
}

// ---------------- bucket-count exclusive scan (dense CSR bases) ------------

__global__ __launch_bounds__(512) void k_bscan(const int* __restrict__ bcur,
                                               int* __restrict__ gbase) {
    const int t = threadIdx.x;
    const int lane = t & 63, wid = t >> 6;
    int v[4]; int s = 0;
#pragma unroll
    for (int k = 0; k < 4; ++k) {
        int b = t * 4 + k;
        v[k] = (b < NB) ? (bcur[b] - b * BCAP) : 0;
        s += v[k];
    }
    int x = s;
#pragma unroll
    for (int off = 1; off < 64; off <<= 1) {
        int y = __shfl_up(x, off, 64);
        if (lane >= off) x += y;
    }
    __shared__ int wsum[8], wexc[8];
    if (lane == 63) wsum[wid] = x;
    __syncthreads();
    if (t == 0) { int a = 0; for (int k = 0; k < 8; ++k) { wexc[k] = a; a += wsum[k]; } }
    __syncthreads();
    int base = wexc[wid] + x - s;    // exclusive prefix for this thread's 4
#pragma unroll
    for (int k = 0; k < 4; ++k) {
        int b = t * 4 + k;
        if (b < NB) gbase[b] = base;
        base += v[k];
    }
}

// ---------------- per-bucket: counts, rowbeg/rowend, dinv, DENSE scatter ---

__global__ __launch_bounds__(256) void k_csr(const int* __restrict__ bcur,
                                             const int* __restrict__ ebuf,
                                             const int* __restrict__ gbase,
                                             int* __restrict__ rowbeg,
                                             int* __restrict__ rowend,
                                             float* __restrict__ dinv,
                                             int* __restrict__ csr, int n) {
    __shared__ int lcnt[BSZ];
    __shared__ int lofs[BSZ];
    const int b = blockIdx.x, t = threadIdx.x;
    if (t < BSZ) lcnt[t] = 0;
    __syncthreads();
    const int beg = b * BCAP, end = bcur[b];
    const int dbase = gbase[b];
    for (int j = beg + t; j < end; j += 256) atomicAdd(&lcnt[ebuf[j] & 63], 1);
    __syncthreads();
    if (t < BSZ) {                       // wave 0 only (threads 0..63)
        int c = lcnt[t];
        int x = c;
#pragma unroll
        for (int off = 1; off < 64; off <<= 1) {
            int y = __shfl_up(x, off, 64);
            if (t >= off) x += y;
        }
        int exc = x - c;                 // exclusive prefix within bucket
        int node = b * BSZ + t;
        if (node < n) {
            rowbeg[node] = dbase + exc;
            rowend[node] = dbase + exc + c;
            dinv[node] = rsqrtf((float)c + 1.0f);   // +1 self-loop
        }
        lofs[t] = dbase + exc;
    }
    __syncthreads();
    for (int j = beg + t; j < end; j += 256) {
        int e = ebuf[j];
        int pos = atomicAdd(&lofs[e & 63], 1);
        csr[pos] = e >> 6;
    }
}

// ---------------- MFMA GEMM layer 1: G = bf16((X @ W1) * dinv[row]) --------

__global__ __launch_bounds__(256) void k_gemm128m(const float* __restrict__ X,
                                                  const unsigned short* __restrict__ W1t,
                                                  const float* __restrict__ dinv,
                                                  unsigned* __restrict__ G, int M) {
    __shared__ float cls[4 * 16 * 132];    // per-wave [16][132] (pad: 2-way max)
    const int t = threadIdx.x;
    const int w = t >> 6, lane = t & 63;
    const int quad = lane >> 4, m16 = lane & 15;
    const int row0 = blockIdx.x * 64 + w * 16;
    int arow = row0 + m16; if (arow >= M) arow = M - 1;

    short8 afrag[4];
#pragma unroll
    for (int ks = 0; ks < 4; ++ks) {
        const float* p = X + (size_t)arow * 128 + ks * 32 + quad * 8;
        float4 u0 = ((const float4*)p)[0];
        float4 u1 = ((const float4*)p)[1];
        short8 a;
        a[0] = (short)f2bf(u0.x); a[1] = (short)f2bf(u0.y);
        a[2] = (short)f2bf(u0.z); a[3] = (short)f2bf(u0.w);
        a[4] = (short)f2bf(u1.x); a[5] = (short)f2bf(u1.y);
        a[6] = (short)f2bf(u1.z); a[7] = (short)f2bf(u1.w);
        afrag[ks] = a;
    }
    float* myc = cls + w * 16 * 132;
#pragma unroll
    for (int nt = 0; nt < 8; ++nt) {
        float4v acc = {0.f, 0.f, 0.f, 0.f};
#pragma unroll
        for (int ks = 0; ks < 4; ++ks) {
            const short8 b = *((const short8*)(W1t + (size_t)(nt * 16 + m16) * 128 + ks * 32 + quad * 8));
            acc = __builtin_amdgcn_mfma_f32_16x16x32_bf16(afrag[ks], b, acc, 0, 0, 0);
        }
#pragma unroll
        for (int r = 0; r < 4; ++r)
            myc[(quad * 4 + r) * 132 + nt * 16 + m16] = acc[r];
    }
    __syncthreads();
    // pack + coalesced store: 16 rows x 32 uint2 chunks = 512 items, 8/lane
#pragma unroll
    for (int i = 0; i < 8; ++i) {
        int idx = i * 64 + lane;
        int r = idx >> 5, c = idx & 31;
        int grow = row0 + r;
        if (grow < M) {
            float4 v = *((const float4*)(myc + r * 132 + c * 4));
            float s = dinv[grow];
            uint2 p;
            p.x = (unsigned)f2bf(v.x * s) | ((unsigned)f2bf(v.y * s) << 16);
            p.y = (unsigned)f2bf(v.z * s) | ((unsigned)f2bf(v.w * s) << 16);
            ((uint2*)G)[(size_t)grow * 32 + c] = p;
        }
    }
}

// ---------------- MFMA GEMM layer 2: G = bf16((Xbf16 @ W2) * dinv[row]) ----

__global__ __launch_bounds__(256) void k_gemm64m(const unsigned short* __restrict__ X,
                                                 const unsigned short* __restrict__ W2t,
                                                 const float* __restrict__ dinv,
                                                 unsigned* __restrict__ G, int M) {
    __shared__ float cls[4 * 16 * 68];     // per-wave [16][68]
    const int t = threadIdx.x;
    const int w = t >> 6, lane = t & 63;
    const int quad = lane >> 4, m16 = lane & 15;
    const int row0 = blockIdx.x * 64 + w * 16;
    int arow = row0 + m16; if (arow >= M) arow = M - 1;

    short8 afrag[4];
#pragma unroll
    for (int ks = 0; ks < 4; ++ks)
        afrag[ks] = *((const short8*)(X + (size_t)arow * 128 + ks * 32 + quad * 8));

    float* myc = cls + w * 16 * 68;
#pragma unroll
    for (int nt = 0; nt < 4; ++nt) {
        float4v acc = {0.f, 0.f, 0.f, 0.f};
#pragma unroll
        for (int ks = 0; ks < 4; ++ks) {
            const short8 b = *((const short8*)(W2t + (size_t)(nt * 16 + m16) * 128 + ks * 32 + quad * 8));
            acc = __builtin_amdgcn_mfma_f32_16x16x32_bf16(afrag[ks], b, acc, 0, 0, 0);
        }
#pragma unroll
        for (int r = 0; r < 4; ++r)
            myc[(quad * 4 + r) * 68 + nt * 16 + m16] = acc[r];
    }
    __syncthreads();
    // pack + store: 16 rows x 16 uint2 chunks = 256 items, 4/lane
#pragma unroll
    for (int i = 0; i < 4; ++i) {
        int idx = i * 64 + lane;
        int r = idx >> 4, c = idx & 15;
        int grow = row0 + r;
        if (grow < M) {
            float4 v = *((const float4*)(myc + r * 68 + c * 4));
            float s = dinv[grow];
            uint2 p;
            p.x = (unsigned)f2bf(v.x * s) | ((unsigned)f2bf(v.y * s) << 16);
            p.y = (unsigned)f2bf(v.z * s) | ((unsigned)f2bf(v.w * s) << 16);
            ((uint2*)G)[(size_t)grow * 16 + c] = p;
        }
    }
}

// ---------------- gather + fused epilogue, uint4 loads ---------------------
// Cap-mechanism probe: same bytes, HALF the load instructions (uint4 16B/lane
// instead of uint2 8B).  Layer 1: quarter-wave per edge (16 lanes x 16B =
// 256-B row), 4 edges per wave-instruction.
// out = bf16(relu(dinv*(agg+g) + bias))

__global__ __launch_bounds__(256) void k_gather128(const int* __restrict__ rowbeg,
                                                   const int* __restrict__ rowend,
                                                   const int* __restrict__ csr,
                                                   const unsigned* __restrict__ G,
                                                   const float* __restrict__ dinv,
                                                   const float* __restrict__ bias,
                                                   unsigned* __restrict__ OUT,
                                                   int n, int nwaves) {
    const int wid = blockIdx.x * 4 + (threadIdx.x >> 6);
    const int lane = threadIdx.x & 63;
    const int sub = lane & 15;           // 16-B chunk within 256-B row
    const int qh = lane >> 4;            // edge slot 0..3
    for (int node = wid; node < n; node += nwaves) {
        const int beg = rowbeg[node];
        const int end = rowend[node];
        float a0 = 0.f, a1 = 0.f, a2 = 0.f, a3 = 0.f;
        float a4 = 0.f, a5 = 0.f, a6 = 0.f, a7 = 0.f;
        for (int c = beg; c < end; c += 64) {
            int ec = end - c; if (ec > 64) ec = 64;
            const int idx = csr[c + ((lane < ec) ? lane : 0)];
            int pb = 0;
            for (; pb + 16 <= ec; pb += 16) {          // full groups: no predication
#pragma unroll
                for (int q = 0; q < 4; ++q) {
                    int s = __shfl(idx, pb + 4 * q + qh, 64);
                    uint4 v = *((const uint4*)(G + (size_t)s * 64 + 4 * sub));
                    a0 += bfl(v.x); a1 += bfh(v.x); a2 += bfl(v.y); a3 += bfh(v.y);
                    a4 += bfl(v.z); a5 += bfh(v.z); a6 += bfl(v.w); a7 += bfh(v.w);
                }
            }
            if (pb < ec) {                             // predicated tail group
#pragma unroll
                for (int q = 0; q < 4; ++q) {
                    int e = pb + 4 * q + qh;
                    bool valid = e < ec;
                    int s = __shfl(idx, valid ? e : 0, 64);
                    uint4 v = *((const uint4*)(G + (size_t)s * 64 + 4 * sub));
                    if (valid) {
                        a0 += bfl(v.x); a1 += bfh(v.x); a2 += bfl(v.y); a3 += bfh(v.y);
                        a4 += bfl(v.z); a5 += bfh(v.z); a6 += bfl(v.w); a7 += bfh(v.w);
                    }
                }
            }
        }
        a0 += __shfl_xor(a0, 16, 64); a0 += __shfl_xor(a0, 32, 64);
        a1 += __shfl_xor(a1, 16, 64); a1 += __shfl_xor(a1, 32, 64);
        a2 += __shfl_xor(a2, 16, 64); a2 += __shfl_xor(a2, 32, 64);
        a3 += __shfl_xor(a3, 16, 64); a3 += __shfl_xor(a3, 32, 64);
        a4 += __shfl_xor(a4, 16, 64); a4 += __shfl_xor(a4, 32, 64);
        a5 += __shfl_xor(a5, 16, 64); a5 += __shfl_xor(a5, 32, 64);
        a6 += __shfl_xor(a6, 16, 64); a6 += __shfl_xor(a6, 32, 64);
        a7 += __shfl_xor(a7, 16, 64); a7 += __shfl_xor(a7, 32, 64);
        if (qh == 0) {
            uint4 vs = *((const uint4*)(G + (size_t)node * 64 + 4 * sub));  // self-loop
            a0 += bfl(vs.x); a1 += bfh(vs.x); a2 += bfl(vs.y); a3 += bfh(vs.y);
            a4 += bfl(vs.z); a5 += bfh(vs.z); a6 += bfl(vs.w); a7 += bfh(vs.w);
            const float di = dinv[node];
            const float4 bv0 = ((const float4*)bias)[2 * sub];
            const float4 bv1 = ((const float4*)bias)[2 * sub + 1];
            float r0 = fmaf(a0, di, bv0.x), r1 = fmaf(a1, di, bv0.y);
            float r2 = fmaf(a2, di, bv0.z), r3 = fmaf(a3, di, bv0.w);
            float r4 = fmaf(a4, di, bv1.x), r5 = fmaf(a5, di, bv1.y);
            float r6 = fmaf(a6, di, bv1.z), r7 = fmaf(a7, di, bv1.w);
            r0 = fmaxf(r0, 0.f); r1 = fmaxf(r1, 0.f); r2 = fmaxf(r2, 0.f); r3 = fmaxf(r3, 0.f);
            r4 = fmaxf(r4, 0.f); r5 = fmaxf(r5, 0.f); r6 = fmaxf(r6, 0.f); r7 = fmaxf(r7, 0.f);
            uint4 p;
            p.x = (unsigned)f2bf(r0) | ((unsigned)f2bf(r1) << 16);
            p.y = (unsigned)f2bf(r2) | ((unsigned)f2bf(r3) << 16);
            p.z = (unsigned)f2bf(r4) | ((unsigned)f2bf(r5) << 16);
            p.w = (unsigned)f2bf(r6) | ((unsigned)f2bf(r7) << 16);
            ((uint4*)OUT)[(size_t)node * 16 + sub] = p;
        }
    }
}

// Layer 2 (128-B rows): eighth-wave per edge (8 lanes x uint4), 8 edges per
// wave-instruction.  out = fp32(dinv*(agg+g) + bias)

__global__ __launch_bounds__(256) void k_gather64(const int* __restrict__ rowbeg,
                                                  const int* __restrict__ rowend,
                                                  const int* __restrict__ csr,
                                                  const unsigned* __restrict__ G,
                                                  const float* __restrict__ dinv,
                                                  const float* __restrict__ bias,
                                                  float* __restrict__ OUT,
                                                  int n, int nwaves) {
    const int wid = blockIdx.x * 4 + (threadIdx.x >> 6);
    const int lane = threadIdx.x & 63;
    const int sub = lane & 7;            // 16-B chunk within 128-B row
    const int oh = lane >> 3;            // edge slot 0..7
    for (int node = wid; node < n; node += nwaves) {
        const int beg = rowbeg[node];
        const int end = rowend[node];
        float a0 = 0.f, a1 = 0.f, a2 = 0.f, a3 = 0.f;
        float a4 = 0.f, a5 = 0.f, a6 = 0.f, a7 = 0.f;
        for (int c = beg; c < end; c += 64) {
            int ec = end - c; if (ec > 64) ec = 64;
            const int idx = csr[c + ((lane < ec) ? lane : 0)];
            int pb = 0;
            for (; pb + 32 <= ec; pb += 32) {          // full groups: no predication
#pragma unroll
                for (int q = 0; q < 4; ++q) {
                    int s = __shfl(idx, pb + 8 * q + oh, 64);
                    uint4 v = *((const uint4*)(G + (size_t)s * 32 + 4 * sub));
                    a0 += bfl(v.x); a1 += bfh(v.x); a2 += bfl(v.y); a3 += bfh(v.y);
                    a4 += bfl(v.z); a5 += bfh(v.z); a6 += bfl(v.w); a7 += bfh(v.w);
                }
            }
            if (pb < ec) {                             // predicated tail group
#pragma unroll
                for (int q = 0; q < 4; ++q) {
                    int e = pb + 8 * q + oh;
                    bool valid = e < ec;
                    int s = __shfl(idx, valid ? e : 0, 64);
                    uint4 v = *((const uint4*)(G + (size_t)s * 32 + 4 * sub));
                    if (valid) {
                        a0 += bfl(v.x); a1 += bfh(v.x); a2 += bfl(v.y); a3 += bfh(v.y);
                        a4 += bfl(v.z); a5 += bfh(v.z); a6 += bfl(v.w); a7 += bfh(v.w);
                    }
                }
            }
        }
        a0 += __shfl_xor(a0, 8, 64); a0 += __shfl_xor(a0, 16, 64); a0 += __shfl_xor(a0, 32, 64);
        a1 += __shfl_xor(a1, 8, 64); a1 += __shfl_xor(a1, 16, 64); a1 += __shfl_xor(a1, 32, 64);
        a2 += __shfl_xor(a2, 8, 64); a2 += __shfl_xor(a2, 16, 64); a2 += __shfl_xor(a2, 32, 64);
        a3 += __shfl_xor(a3, 8, 64); a3 += __shfl_xor(a3, 16, 64); a3 += __shfl_xor(a3, 32, 64);
        a4 += __shfl_xor(a4, 8, 64); a4 += __shfl_xor(a4, 16, 64); a4 += __shfl_xor(a4, 32, 64);
        a5 += __shfl_xor(a5, 8, 64); a5 += __shfl_xor(a5, 16, 64); a5 += __shfl_xor(a5, 32, 64);
        a6 += __shfl_xor(a6, 8, 64); a6 += __shfl_xor(a6, 16, 64); a6 += __shfl_xor(a6, 32, 64);
        a7 += __shfl_xor(a7, 8, 64); a7 += __shfl_xor(a7, 16, 64); a7 += __shfl_xor(a7, 32, 64);
        if (oh == 0) {
            uint4 vs = *((const uint4*)(G + (size_t)node * 32 + 4 * sub));  // self-loop
            a0 += bfl(vs.x); a1 += bfh(vs.x); a2 += bfl(vs.y); a3 += bfh(vs.y);
            a4 += bfl(vs.z); a5 += bfh(vs.z); a6 += bfl(vs.w); a7 += bfh(vs.w);
            const float di = dinv[node];
            const float4 bv0 = ((const float4*)bias)[2 * sub];
            const float4 bv1 = ((const float4*)bias)[2 * sub + 1];
            float4 r0v, r1v;
            r0v.x = fmaf(a0, di, bv0.x); r0v.y = fmaf(a1, di, bv0.y);
            r0v.z = fmaf(a2, di, bv0.z); r0v.w = fmaf(a3, di, bv0.w);
            r1v.x = fmaf(a4, di, bv1.x); r1v.y = fmaf(a5, di, bv1.y);
            r1v.z = fmaf(a6, di, bv1.z); r1v.w = fmaf(a7, di, bv1.w);
            ((float4*)OUT)[(size_t)node * 16 + 2 * sub] = r0v;
            ((float4*)OUT)[(size_t)node * 16 + 2 * sub + 1] = r1v;
        }
    }
}

// ---------------- launch ----------------

extern "C" void kernel_launch(void* const* d_in, const int* in_sizes, int n_in,
                              void* d_out, int out_size, void* d_ws, size_t ws_size,
                              hipStream_t stream) {
    const float* x  = (const float*)d_in[0];
    const float* W1 = (const float*)d_in[1];
    const float* b1 = (const float*)d_in[2];
    const float* W2 = (const float*)d_in[3];
    const float* b2 = (const float*)d_in[4];
    const int*   ei = (const int*)d_in[5];   // [2, E] int32
    const int* src = ei;
    const int* dst = ei + EE;
    float* out = (float*)d_out;

    // ws layout (~84 MB, within proven envelope)
    char* p = (char*)d_ws;
    unsigned* g1b = (unsigned*)p;             p += (size_t)NN * 64 * 4;  // 25.6MB [N][64]u
    unsigned* h1b = (unsigned*)p;             p += (size_t)NN * 64 * 4;  // 25.6MB [N][128]bf16
    unsigned* g2b = (unsigned*)p;             p += (size_t)NN * 32 * 4;  // 12.8MB [N][32]u
    unsigned short* w1t = (unsigned short*)p; p += 16384 * 2;
    unsigned short* w2t = (unsigned short*)p; p += 8192 * 2;
    int*   bcur   = (int*)p;                  p += ((size_t)NB * 4 + 15) & ~(size_t)15;
    int*   gbase  = (int*)p;                  p += ((size_t)NB * 4 + 15) & ~(size_t)15;
    int*   rowbeg = (int*)p;                  p += (size_t)NN * 4;
    int*   rowend = (int*)p;                  p += (size_t)NN * 4;
    float* dinv   = (float*)p;                p += (size_t)NN * 4;
    int*   ebuf   = (int*)p;                  p += (size_t)NB * BCAP * 4; // 12.8MB
    int*   csr    = (int*)p;                  p += (size_t)EE * 4;        // 6.4MB dense

    constexpr int NWG = GB * 4;                       // gather waves
    constexpr int IB = (24576 + NB + 255) / 256;      // init blocks

    k_init<<<IB, 256, 0, stream>>>(W1, W2, w1t, w2t, bcur);
    k_bin<<<(EE + TILE - 1) / TILE, 256, 0, stream>>>(src, dst, bcur, ebuf, EE);
    k_bscan<<<1, 512, 0, stream>>>(bcur, gbase);
    k_csr<<<NB, 256, 0, stream>>>(bcur, ebuf, gbase, rowbeg, rowend, dinv, csr, NN);

    // layer 1: g1b = bf16((x@W1)*dinv) ; h1b = bf16(relu(dinv*(agg+g1)+b1))
    k_gemm128m<<<(NN + 63) / 64, 256, 0, stream>>>(x, w1t, dinv, g1b, NN);
    k_gather128<<<GB, 256, 0, stream>>>(rowbeg, rowend, csr, g1b, dinv, b1, h1b, NN, NWG);

    // layer 2: g2b = bf16((h1b@W2)*dinv) ; out = dinv*(agg+g2)+b2  [fp32]
    k_gemm64m<<<(NN + 63) / 64, 256, 0, stream>>>((const unsigned short*)h1b, w2t, dinv, g2b, NN);
    k_gather64<<<GB, 256, 0, stream>>>(rowbeg, rowend, csr, g2b, dinv, b2, out, NN, NWG);
}

// Round 13
// 311.863 us; speedup vs baseline: 1.0169x; 1.0169x over previous
//
#include <hip/hip_runtime.h>

static constexpr int NN = 100000;    // nodes
static constexpr int EE = 1600000;   // edges (before self-loops)
static constexpr int BSZ = 64;       // nodes per bucket
static constexpr int NB = (NN + BSZ - 1) / BSZ;   // 1563 buckets
static constexpr int BCAP = 2048;    // fixed bucket capacity (mean 1024, 32 sigma)
static constexpr int TILE = 4096;    // edges per binning block (391 blocks, r11-proven)
static constexpr int GB = 2048;      // gather blocks (persistent)

// ---- bf16 helpers (storage-only; math stays fp32) ----

__device__ __forceinline__ unsigned short f2bf(float f) {   // round-to-nearest-even
    unsigned u = __float_as_uint(f);
    u += 0x7FFFu + ((u >> 16) & 1u);
    return (unsigned short)(u >> 16);
}
__device__ __forceinline__ float bfl(unsigned u) { return __uint_as_float(u << 16); }
__device__ __forceinline__ float bfh(unsigned u) { return __uint_as_float(u & 0xFFFF0000u); }

typedef __attribute__((ext_vector_type(8))) short short8;    // 8 bf16 (4 VGPRs)
typedef __attribute__((ext_vector_type(4))) float float4v;   // MFMA acc

// ---------------- init: W^T bf16 prep + bucket cursor bases ----------------

__global__ __launch_bounds__(256) void k_init(const float* __restrict__ W1,
                                              const float* __restrict__ W2,
                                              unsigned short* __restrict__ W1t,
                                              unsigned short* __restrict__ W2t,
                                              int* __restrict__ bcur) {
    int idx = blockIdx.x * 256 + threadIdx.x;
    if (idx < 16384) {
        int n = idx >> 7, k = idx & 127;
        W1t[idx] = f2bf(W1[k * 128 + n]);
    } else if (idx < 24576) {
        int j = idx - 16384;
        int n = j >> 7, k = j & 127;
        W2t[j] = f2bf(W2[k * 64 + n]);
    } else if (idx < 24576 + NB) {
        int b = idx - 24576;
        bcur[b] = b * BCAP;
    }
}

// ---------------- bin edges into fixed-stride bucket chunks ----------------
// Per-tile LDS histogram -> one global atomicAdd per (bucket,tile) chunk ->
// chunk-local writes (line-combining).  Entry = (src<<6) | local_dst.
// TILE=4096: block-count marginal cost measured ~26ns/block (r5/r10 A/B);
// fewer blocks = shorter per-bucket cursor atomic chains.

__global__ __launch_bounds__(256) void k_bin(const int* __restrict__ src,
                                             const int* __restrict__ dst,
                                             int* __restrict__ bcur,
                                             int* __restrict__ ebuf, int E) {
    constexpr int K = TILE / 256;  // 16 edges per thread
    __shared__ int lcnt[NB];
    __shared__ int lbase[NB];
    const int t = threadIdx.x;
    const int e0 = blockIdx.x * TILE;

    for (int i = t; i < NB; i += 256) lcnt[i] = 0;
    __syncthreads();

    int dreg[K], ofs[K];
#pragma unroll
    for (int k = 0; k < K; ++k) {
        int e = e0 + k * 256 + t;
        if (e < E) {
            int d = dst[e];
            dreg[k] = d;
            ofs[k] = atomicAdd(&lcnt[d >> 6], 1);
        } else dreg[k] = -1;
    }
    __syncthreads();

    for (int i = t; i < NB; i += 256) {
        int c = lcnt[i];
        lbase[i] = c ? atomicAdd(&bcur[i], c) : 0;
    }
    __syncthreads();

#pragma unroll
    for (int k = 0; k < K; ++k) {
        if (dreg[k] >= 0) {
            int e = e0 + k * 256 + t;
            int s = src[e];
            int b = dreg[k] >> 6;
            ebuf[lbase[b] + ofs[k]] = (s << 6) | (dreg[k] & 63);
        }
    }
}

// ---------------- bucket-count exclusive scan (dense CSR bases) ------------

__global__ __launch_bounds__(512) void k_bscan(const int* __restrict__ bcur,
                                               int* __restrict__ gbase) {
    const int t = threadIdx.x;
    const int lane = t & 63, wid = t >> 6;
    int v[4]; int s = 0;
#pragma unroll
    for (int k = 0; k < 4; ++k) {
        int b = t * 4 + k;
        v[k] = (b < NB) ? (bcur[b] - b * BCAP) : 0;
        s += v[k];
    }
    int x = s;
#pragma unroll
    for (int off = 1; off < 64; off <<= 1) {
        int y = __shfl_up(x, off, 64);
        if (lane >= off) x += y;
    }
    __shared__ int wsum[8], wexc[8];
    if (lane == 63) wsum[wid] = x;
    __syncthreads();
    if (t == 0) { int a = 0; for (int k = 0; k < 8; ++k) { wexc[k] = a; a += wsum[k]; } }
    __syncthreads();
    int base = wexc[wid] + x - s;    // exclusive prefix for this thread's 4
#pragma unroll
    for (int k = 0; k < 4; ++k) {
        int b = t * 4 + k;
        if (b < NB) gbase[b] = base;
        base += v[k];
    }
}

// ---------------- per-bucket: counts, rowbeg/rowend, dinv, DENSE scatter ---

__global__ __launch_bounds__(256) void k_csr(const int* __restrict__ bcur,
                                             const int* __restrict__ ebuf,
                                             const int* __restrict__ gbase,
                                             int* __restrict__ rowbeg,
                                             int* __restrict__ rowend,
                                             float* __restrict__ dinv,
                                             int* __restrict__ csr, int n) {
    __shared__ int lcnt[BSZ];
    __shared__ int lofs[BSZ];
    const int b = blockIdx.x, t = threadIdx.x;
    if (t < BSZ) lcnt[t] = 0;
    __syncthreads();
    const int beg = b * BCAP, end = bcur[b];
    const int dbase = gbase[b];
    for (int j = beg + t; j < end; j += 256) atomicAdd(&lcnt[ebuf[j] & 63], 1);
    __syncthreads();
    if (t < BSZ) {                       // wave 0 only (threads 0..63)
        int c = lcnt[t];
        int x = c;
#pragma unroll
        for (int off = 1; off < 64; off <<= 1) {
            int y = __shfl_up(x, off, 64);
            if (t >= off) x += y;
        }
        int exc = x - c;                 // exclusive prefix within bucket
        int node = b * BSZ + t;
        if (node < n) {
            rowbeg[node] = dbase + exc;
            rowend[node] = dbase + exc + c;
            dinv[node] = rsqrtf((float)c + 1.0f);   // +1 self-loop
        }
        lofs[t] = dbase + exc;
    }
    __syncthreads();
    for (int j = beg + t; j < end; j += 256) {
        int e = ebuf[j];
        int pos = atomicAdd(&lofs[e & 63], 1);
        csr[pos] = e >> 6;
    }
}

// ---------------- MFMA GEMM layer 1: G = bf16((X @ W1) * dinv[row]) --------

__global__ __launch_bounds__(256) void k_gemm128m(const float* __restrict__ X,
                                                  const unsigned short* __restrict__ W1t,
                                                  const float* __restrict__ dinv,
                                                  unsigned* __restrict__ G, int M) {
    __shared__ float cls[4 * 16 * 132];    // per-wave [16][132] (pad: 2-way max)
    const int t = threadIdx.x;
    const int w = t >> 6, lane = t & 63;
    const int quad = lane >> 4, m16 = lane & 15;
    const int row0 = blockIdx.x * 64 + w * 16;
    int arow = row0 + m16; if (arow >= M) arow = M - 1;

    short8 afrag[4];
#pragma unroll
    for (int ks = 0; ks < 4; ++ks) {
        const float* p = X + (size_t)arow * 128 + ks * 32 + quad * 8;
        float4 u0 = ((const float4*)p)[0];
        float4 u1 = ((const float4*)p)[1];
        short8 a;
        a[0] = (short)f2bf(u0.x); a[1] = (short)f2bf(u0.y);
        a[2] = (short)f2bf(u0.z); a[3] = (short)f2bf(u0.w);
        a[4] = (short)f2bf(u1.x); a[5] = (short)f2bf(u1.y);
        a[6] = (short)f2bf(u1.z); a[7] = (short)f2bf(u1.w);
        afrag[ks] = a;
    }
    float* myc = cls + w * 16 * 132;
#pragma unroll
    for (int nt = 0; nt < 8; ++nt) {
        float4v acc = {0.f, 0.f, 0.f, 0.f};
#pragma unroll
        for (int ks = 0; ks < 4; ++ks) {
            const short8 b = *((const short8*)(W1t + (size_t)(nt * 16 + m16) * 128 + ks * 32 + quad * 8));
            acc = __builtin_amdgcn_mfma_f32_16x16x32_bf16(afrag[ks], b, acc, 0, 0, 0);
        }
#pragma unroll
        for (int r = 0; r < 4; ++r)
            myc[(quad * 4 + r) * 132 + nt * 16 + m16] = acc[r];
    }
    __syncthreads();
    // pack + coalesced store: 16 rows x 32 uint2 chunks = 512 items, 8/lane
#pragma unroll
    for (int i = 0; i < 8; ++i) {
        int idx = i * 64 + lane;
        int r = idx >> 5, c = idx & 31;
        int grow = row0 + r;
        if (grow < M) {
            float4 v = *((const float4*)(myc + r * 132 + c * 4));
            float s = dinv[grow];
            uint2 p;
            p.x = (unsigned)f2bf(v.x * s) | ((unsigned)f2bf(v.y * s) << 16);
            p.y = (unsigned)f2bf(v.z * s) | ((unsigned)f2bf(v.w * s) << 16);
            ((uint2*)G)[(size_t)grow * 32 + c] = p;
        }
    }
}

// ---------------- MFMA GEMM layer 2: G = bf16((Xbf16 @ W2) * dinv[row]) ----

__global__ __launch_bounds__(256) void k_gemm64m(const unsigned short* __restrict__ X,
                                                 const unsigned short* __restrict__ W2t,
                                                 const float* __restrict__ dinv,
                                                 unsigned* __restrict__ G, int M) {
    __shared__ float cls[4 * 16 * 68];     // per-wave [16][68]
    const int t = threadIdx.x;
    const int w = t >> 6, lane = t & 63;
    const int quad = lane >> 4, m16 = lane & 15;
    const int row0 = blockIdx.x * 64 + w * 16;
    int arow = row0 + m16; if (arow >= M) arow = M - 1;

    short8 afrag[4];
#pragma unroll
    for (int ks = 0; ks < 4; ++ks)
        afrag[ks] = *((const short8*)(X + (size_t)arow * 128 + ks * 32 + quad * 8));

    float* myc = cls + w * 16 * 68;
#pragma unroll
    for (int nt = 0; nt < 4; ++nt) {
        float4v acc = {0.f, 0.f, 0.f, 0.f};
#pragma unroll
        for (int ks = 0; ks < 4; ++ks) {
            const short8 b = *((const short8*)(W2t + (size_t)(nt * 16 + m16) * 128 + ks * 32 + quad * 8));
            acc = __builtin_amdgcn_mfma_f32_16x16x32_bf16(afrag[ks], b, acc, 0, 0, 0);
        }
#pragma unroll
        for (int r = 0; r < 4; ++r)
            myc[(quad * 4 + r) * 68 + nt * 16 + m16] = acc[r];
    }
    __syncthreads();
    // pack + store: 16 rows x 16 uint2 chunks = 256 items, 4/lane
#pragma unroll
    for (int i = 0; i < 4; ++i) {
        int idx = i * 64 + lane;
        int r = idx >> 4, c = idx & 15;
        int grow = row0 + r;
        if (grow < M) {
            float4 v = *((const float4*)(myc + r * 68 + c * 4));
            float s = dinv[grow];
            uint2 p;
            p.x = (unsigned)f2bf(v.x * s) | ((unsigned)f2bf(v.y * s) << 16);
            p.y = (unsigned)f2bf(v.z * s) | ((unsigned)f2bf(v.w * s) << 16);
            ((uint2*)G)[(size_t)grow * 16 + c] = p;
        }
    }
}

// ---------------- gather + fused epilogue ----------------------------------
// Persistent waves; wave per node (grid-stride).
// Layer 1 (256 B rows): half-wave per edge (uint2/lane), 16 edges / 2 KB in
// flight.  uint4 variant measured SLOWER (r12: 84 vs 67 us) — the limit is
// outstanding 64-B sectors per CU, and uint2 keeps occupancy higher.
// out = bf16(relu(dinv*(agg+g) + bias))

__global__ __launch_bounds__(256) void k_gather128(const int* __restrict__ rowbeg,
                                                   const int* __restrict__ rowend,
                                                   const int* __restrict__ csr,
                                                   const unsigned* __restrict__ G,
                                                   const float* __restrict__ dinv,
                                                   const float* __restrict__ bias,
                                                   unsigned* __restrict__ OUT,
                                                   int n, int nwaves) {
    const int wid = blockIdx.x * 4 + (threadIdx.x >> 6);
    const int lane = threadIdx.x & 63;
    const int sub = lane & 31;
    const int half = lane >> 5;
    for (int node = wid; node < n; node += nwaves) {
        const int beg = rowbeg[node];
        const int end = rowend[node];
        float a0 = 0.f, a1 = 0.f, a2 = 0.f, a3 = 0.f;
        for (int c = beg; c < end; c += 64) {
            int ec = end - c; if (ec > 64) ec = 64;
            const int idx = csr[c + ((lane < ec) ? lane : 0)];
            int pb = 0;
            for (; pb + 16 <= ec; pb += 16) {          // full groups: no predication
#pragma unroll
                for (int q = 0; q < 8; ++q) {
                    int s = __shfl(idx, pb + 2 * q + half, 64);
                    uint2 v = *((const uint2*)(G + (size_t)s * 64 + 2 * sub));
                    a0 += bfl(v.x); a1 += bfh(v.x); a2 += bfl(v.y); a3 += bfh(v.y);
                }
            }
            if (pb < ec) {                             // predicated tail group
#pragma unroll
                for (int q = 0; q < 8; ++q) {
                    int e = pb + 2 * q + half;
                    bool valid = e < ec;
                    int s = __shfl(idx, valid ? e : 0, 64);
                    uint2 v = *((const uint2*)(G + (size_t)s * 64 + 2 * sub));
                    if (valid) { a0 += bfl(v.x); a1 += bfh(v.x); a2 += bfl(v.y); a3 += bfh(v.y); }
                }
            }
        }
        a0 += __shfl_xor(a0, 32, 64);
        a1 += __shfl_xor(a1, 32, 64);
        a2 += __shfl_xor(a2, 32, 64);
        a3 += __shfl_xor(a3, 32, 64);
        if (half == 0) {
            uint2 vs = *((const uint2*)(G + (size_t)node * 64 + 2 * sub));  // self-loop
            a0 += bfl(vs.x); a1 += bfh(vs.x); a2 += bfl(vs.y); a3 += bfh(vs.y);
            const float di = dinv[node];
            const float4 bv = ((const float4*)bias)[sub];
            float r0 = fmaf(a0, di, bv.x), r1 = fmaf(a1, di, bv.y);
            float r2 = fmaf(a2, di, bv.z), r3 = fmaf(a3, di, bv.w);
            r0 = fmaxf(r0, 0.f); r1 = fmaxf(r1, 0.f);
            r2 = fmaxf(r2, 0.f); r3 = fmaxf(r3, 0.f);
            uint2 p;
            p.x = (unsigned)f2bf(r0) | ((unsigned)f2bf(r1) << 16);
            p.y = (unsigned)f2bf(r2) | ((unsigned)f2bf(r3) << 16);
            ((uint2*)OUT)[(size_t)node * 32 + sub] = p;
        }
    }
}

// Layer 2 (128 B rows): quarter-wave per edge (16 lanes x uint2), 32 edges /
// 4 KB in flight per wave.  out = fp32(dinv*(agg+g) + bias)

__global__ __launch_bounds__(256) void k_gather64(const int* __restrict__ rowbeg,
                                                  const int* __restrict__ rowend,
                                                  const int* __restrict__ csr,
                                                  const unsigned* __restrict__ G,
                                                  const float* __restrict__ dinv,
                                                  const float* __restrict__ bias,
                                                  float* __restrict__ OUT,
                                                  int n, int nwaves) {
    const int wid = blockIdx.x * 4 + (threadIdx.x >> 6);
    const int lane = threadIdx.x & 63;
    const int sub = lane & 15;
    const int qh = lane >> 4;            // 0..3
    for (int node = wid; node < n; node += nwaves) {
        const int beg = rowbeg[node];
        const int end = rowend[node];
        float a0 = 0.f, a1 = 0.f, a2 = 0.f, a3 = 0.f;
        for (int c = beg; c < end; c += 64) {
            int ec = end - c; if (ec > 64) ec = 64;
            const int idx = csr[c + ((lane < ec) ? lane : 0)];
            int pb = 0;
            for (; pb + 32 <= ec; pb += 32) {          // full groups: no predication
#pragma unroll
                for (int q = 0; q < 8; ++q) {
                    int s = __shfl(idx, pb + 4 * q + qh, 64);
                    uint2 v = ((const uint2*)(G + (size_t)s * 32))[sub];
                    a0 += bfl(v.x); a1 += bfh(v.x); a2 += bfl(v.y); a3 += bfh(v.y);
                }
            }
            if (pb < ec) {                             // predicated tail group
#pragma unroll
                for (int q = 0; q < 8; ++q) {
                    int e = pb + 4 * q + qh;
                    bool valid = e < ec;
                    int s = __shfl(idx, valid ? e : 0, 64);
                    uint2 v = ((const uint2*)(G + (size_t)s * 32))[sub];
                    if (valid) { a0 += bfl(v.x); a1 += bfh(v.x); a2 += bfl(v.y); a3 += bfh(v.y); }
                }
            }
        }
        a0 += __shfl_xor(a0, 16, 64); a0 += __shfl_xor(a0, 32, 64);
        a1 += __shfl_xor(a1, 16, 64); a1 += __shfl_xor(a1, 32, 64);
        a2 += __shfl_xor(a2, 16, 64); a2 += __shfl_xor(a2, 32, 64);
        a3 += __shfl_xor(a3, 16, 64); a3 += __shfl_xor(a3, 32, 64);
        if (qh == 0) {
            uint2 vs = ((const uint2*)(G + (size_t)node * 32))[sub];   // self-loop
            a0 += bfl(vs.x); a1 += bfh(vs.x); a2 += bfl(vs.y); a3 += bfh(vs.y);
            const float di = dinv[node];
            const float4 bv = ((const float4*)bias)[sub];
            float4 r;
            r.x = fmaf(a0, di, bv.x);
            r.y = fmaf(a1, di, bv.y);
            r.z = fmaf(a2, di, bv.z);
            r.w = fmaf(a3, di, bv.w);
            ((float4*)OUT)[(size_t)node * 16 + sub] = r;
        }
    }
}

// ---------------- launch ----------------

extern "C" void kernel_launch(void* const* d_in, const int* in_sizes, int n_in,
                              void* d_out, int out_size, void* d_ws, size_t ws_size,
                              hipStream_t stream) {
    const float* x  = (const float*)d_in[0];
    const float* W1 = (const float*)d_in[1];
    const float* b1 = (const float*)d_in[2];
    const float* W2 = (const float*)d_in[3];
    const float* b2 = (const float*)d_in[4];
    const int*   ei = (const int*)d_in[5];   // [2, E] int32
    const int* src = ei;
    const int* dst = ei + EE;
    float* out = (float*)d_out;

    // ws layout (~84 MB, within proven envelope)
    char* p = (char*)d_ws;
    unsigned* g1b = (unsigned*)p;             p += (size_t)NN * 64 * 4;  // 25.6MB [N][64]u
    unsigned* h1b = (unsigned*)p;             p += (size_t)NN * 64 * 4;  // 25.6MB [N][128]bf16
    unsigned* g2b = (unsigned*)p;             p += (size_t)NN * 32 * 4;  // 12.8MB [N][32]u
    unsigned short* w1t = (unsigned short*)p; p += 16384 * 2;
    unsigned short* w2t = (unsigned short*)p; p += 8192 * 2;
    int*   bcur   = (int*)p;                  p += ((size_t)NB * 4 + 15) & ~(size_t)15;
    int*   gbase  = (int*)p;                  p += ((size_t)NB * 4 + 15) & ~(size_t)15;
    int*   rowbeg = (int*)p;                  p += (size_t)NN * 4;
    int*   rowend = (int*)p;                  p += (size_t)NN * 4;
    float* dinv   = (float*)p;                p += (size_t)NN * 4;
    int*   ebuf   = (int*)p;                  p += (size_t)NB * BCAP * 4; // 12.8MB
    int*   csr    = (int*)p;                  p += (size_t)EE * 4;        // 6.4MB dense

    constexpr int NWG = GB * 4;                       // gather waves
    constexpr int IB = (24576 + NB + 255) / 256;      // init blocks

    k_init<<<IB, 256, 0, stream>>>(W1, W2, w1t, w2t, bcur);
    k_bin<<<(EE + TILE - 1) / TILE, 256, 0, stream>>>(src, dst, bcur, ebuf, EE);
    k_bscan<<<1, 512, 0, stream>>>(bcur, gbase);
    k_csr<<<NB, 256, 0, stream>>>(bcur, ebuf, gbase, rowbeg, rowend, dinv, csr, NN);

    // layer 1: g1b = bf16((x@W1)*dinv) ; h1b = bf16(relu(dinv*(agg+g1)+b1))
    k_gemm128m<<<(NN + 63) / 64, 256, 0, stream>>>(x, w1t, dinv, g1b, NN);
    k_gather128<<<GB, 256, 0, stream>>>(rowbeg, rowend, csr, g1b, dinv, b1, h1b, NN, NWG);

    // layer 2: g2b = bf16((h1b@W2)*dinv) ; out = dinv*(agg+g2)+b2  [fp32]
    k_gemm64m<<<(NN + 63) / 64, 256, 0, stream>>>((const unsigned short*)h1b, w2t, dinv, g2b, NN);
    k_gather64<<<GB, 256, 0, stream>>>(rowbeg, rowend, csr, g2b, dinv, b2, out, NN, NWG);
}